// Round 3
// baseline (1118.651 us; speedup 1.0000x reference)
//
#include <hip/hip_runtime.h>
#include <cmath>

// ---------------------------------------------------------------------------
// BrainAgeGATv2: 4-layer GATv2-ish GNN, N=40000 nodes, E=400000 edges, B=100
// graphs, hidden = H*C = 128.
// R1: gat_kernel restructured for memory-level parallelism (chunk-of-16 edge
//     processing, batched gathers, per-chunk softmax rescale); pool split into
//     800-block partial stage + reduction in the head MLP.
// R2: resubmit of R1 (container died before measuring).
// ---------------------------------------------------------------------------

// ---------------- preprocessing ----------------

__global__ __launch_bounds__(256) void init_deg_kernel(int* deg, int n) {
  int v = blockIdx.x * 256 + threadIdx.x;
  if (v < n) deg[v] = 1;  // self-loop
}

__global__ __launch_bounds__(256) void count_kernel(const int* __restrict__ ei,
                                                    const float* __restrict__ eattr,
                                                    int* deg, float* ea_sum, int E) {
  int e = blockIdx.x * 256 + threadIdx.x;
  float v = 0.f;
  if (e < E) {
    atomicAdd(&deg[ei[(size_t)E + e]], 1);  // dst = ei[1][e]
    v = eattr[e];
  }
  __shared__ float red[256];
  red[threadIdx.x] = v;
  __syncthreads();
  for (int off = 128; off > 0; off >>= 1) {
    if (threadIdx.x < off) red[threadIdx.x] += red[threadIdx.x + off];
    __syncthreads();
  }
  if (threadIdx.x == 0) atomicAdd(ea_sum, red[0]);
}

__global__ __launch_bounds__(1024) void scan_kernel(const int* __restrict__ deg,
                                                    int* row_ofs, int n) {
  __shared__ int partial[1024];
  int t = threadIdx.x;
  int per = (n + 1023) / 1024;
  int start = t * per;
  int end = min(start + per, n);
  int s = 0;
  for (int i = start; i < end; i++) s += deg[i];
  partial[t] = s;
  __syncthreads();
  for (int off = 1; off < 1024; off <<= 1) {
    int v = (t >= off) ? partial[t - off] : 0;
    __syncthreads();
    partial[t] += v;
    __syncthreads();
  }
  int run = (t == 0) ? 0 : partial[t - 1];
  for (int i = start; i < end; i++) {
    row_ofs[i] = run;
    run += deg[i];
  }
  if (t == 1023) row_ofs[n] = run;  // total = E + n
}

__global__ __launch_bounds__(256) void copy_int_kernel(const int* __restrict__ src,
                                                       int* __restrict__ dst, int n) {
  int i = blockIdx.x * 256 + threadIdx.x;
  if (i < n) dst[i] = src[i];
}

__global__ __launch_bounds__(256) void fill_kernel(const int* __restrict__ ei,
                                                   const float* __restrict__ eattr,
                                                   const float* __restrict__ ea_sum,
                                                   int* cursor, int* csr_src,
                                                   float* csr_ea, int E, int n) {
  int i = blockIdx.x * 256 + threadIdx.x;
  if (i >= E + n) return;
  int s, d;
  float ev;
  if (i < E) {
    s = ei[i];
    d = ei[(size_t)E + i];
    ev = eattr[i];
  } else {
    s = d = i - E;                       // self loop
    ev = ea_sum[0] * (1.0f / (float)E);  // mean(edge_attr)
  }
  int pos = atomicAdd(&cursor[d], 1);
  csr_src[pos] = s;
  csr_ea[pos] = ev;
}

// ---------------- embed: h0 = relu(x @ W_emb + b_emb), x: N x 4, W: 4 x 64 ----

__global__ __launch_bounds__(256) void embed_kernel(const float* __restrict__ x,
                                                    const float* __restrict__ W,
                                                    const float* __restrict__ bvec,
                                                    float* __restrict__ h0, int n) {
  int idx = blockIdx.x * 256 + threadIdx.x;
  if (idx >= n * 64) return;
  int v = idx >> 6, j = idx & 63;
  float s = bvec[j];
  s += x[v * 4 + 0] * W[j];
  s += x[v * 4 + 1] * W[64 + j];
  s += x[v * 4 + 2] * W[128 + j];
  s += x[v * 4 + 3] * W[192 + j];
  h0[idx] = fmaxf(s, 0.f);
}

// ---------------- GEMM: out = in(N x K) @ W(K x 128) + bias; two W per launch --

__global__ __launch_bounds__(256) void gemm_kernel(const float* __restrict__ in, int K,
                                                   const float* __restrict__ W0,
                                                   const float* __restrict__ W1,
                                                   const float* __restrict__ b0,
                                                   const float* __restrict__ b1,
                                                   float* __restrict__ o0,
                                                   float* __restrict__ o1) {
  const float* W = blockIdx.y ? W1 : W0;
  const float* bias = blockIdx.y ? b1 : b0;
  float* out = blockIdx.y ? o1 : o0;

  __shared__ float hs[64][33];    // 64 rows x 32 k (+1 pad)
  __shared__ float wsm[32][128];  // 32 k x 128 cols

  int t = threadIdx.x;
  int r0 = blockIdx.x * 64;
  int tc = t & 15;  // col-thread: cols tc*8 .. +8
  int tr = t >> 4;  // row-thread: rows tr*4 .. +4

  float acc[4][8];
#pragma unroll
  for (int i = 0; i < 4; i++)
#pragma unroll
    for (int j = 0; j < 8; j++) acc[i][j] = 0.f;

  for (int k0 = 0; k0 < K; k0 += 32) {
// stage in-tile: 64x32 floats (512 float4, 2 per thread)
#pragma unroll
    for (int i = 0; i < 2; i++) {
      int f = t * 2 + i;  // 0..511
      int row = f >> 3;
      int kk = (f & 7) * 4;
      float4 v = *reinterpret_cast<const float4*>(in + (size_t)(r0 + row) * K + k0 + kk);
      hs[row][kk + 0] = v.x;
      hs[row][kk + 1] = v.y;
      hs[row][kk + 2] = v.z;
      hs[row][kk + 3] = v.w;
    }
// stage W-tile: 32x128 floats (1024 float4, 4 per thread)
#pragma unroll
    for (int i = 0; i < 4; i++) {
      int f = t * 4 + i;  // 0..1023
      int kk = f >> 5;
      int c4 = (f & 31) * 4;
      *reinterpret_cast<float4*>(&wsm[kk][c4]) =
          *reinterpret_cast<const float4*>(W + (size_t)(k0 + kk) * 128 + c4);
    }
    __syncthreads();
#pragma unroll 4
    for (int kk = 0; kk < 32; kk++) {
      float a0 = hs[tr * 4 + 0][kk];
      float a1 = hs[tr * 4 + 1][kk];
      float a2 = hs[tr * 4 + 2][kk];
      float a3 = hs[tr * 4 + 3][kk];
      float4 bb0 = *reinterpret_cast<float4*>(&wsm[kk][tc * 8]);
      float4 bb1 = *reinterpret_cast<float4*>(&wsm[kk][tc * 8 + 4]);
      float bv[8] = {bb0.x, bb0.y, bb0.z, bb0.w, bb1.x, bb1.y, bb1.z, bb1.w};
#pragma unroll
      for (int j = 0; j < 8; j++) {
        acc[0][j] += a0 * bv[j];
        acc[1][j] += a1 * bv[j];
        acc[2][j] += a2 * bv[j];
        acc[3][j] += a3 * bv[j];
      }
    }
    __syncthreads();
  }
#pragma unroll
  for (int i = 0; i < 4; i++) {
    int r = r0 + tr * 4 + i;
#pragma unroll
    for (int j = 0; j < 8; j++) {
      out[(size_t)r * 128 + tc * 8 + j] = acc[i][j] + bias[tc * 8 + j];
    }
  }
}

// ---------------- GAT aggregation: wave per node, chunked-MLP online softmax --
// Chunk of 16 edges: lane-parallel index load, batched row gathers (32 loads
// in flight), per-chunk max + single rescale. Removes the per-edge serial
// latency chain that made R0's version latency-bound (VALUBusy 17%).

#define GAT_CHUNK 16

__global__ __launch_bounds__(256) void gat_kernel(
    const float* __restrict__ xl, const float* __restrict__ xr,
    const int* __restrict__ row_ofs, const int* __restrict__ csr_src,
    const float* __restrict__ csr_ea, const float* __restrict__ We_l,
    const float* __restrict__ att_l, const float* __restrict__ bo_l,
    float* __restrict__ z, int n) {
  int wave = threadIdx.x >> 6;
  int lane = threadIdx.x & 63;
  int v = blockIdx.x * 4 + wave;
  if (v >= n) return;

  int c0 = lane, c1 = lane + 64;  // two channels per lane; head = c/16
  float xr0 = xr[(size_t)v * 128 + c0];
  float xr1 = xr[(size_t)v * 128 + c1];
  float we0 = We_l[c0], we1 = We_l[c1];
  float at0 = att_l[c0], at1 = att_l[c1];

  float m0 = -INFINITY, m1 = -INFINITY;
  float d0 = 0.f, d1 = 0.f;
  float acc0 = 0.f, acc1 = 0.f;

  int beg = row_ofs[v], end = row_ofs[v + 1];
  for (int base = beg; base < end; base += GAT_CHUNK) {
    int cnt = min(GAT_CHUNK, end - base);
    // lane-parallel metadata load (lanes 0..cnt-1)
    int sl = (lane < cnt) ? csr_src[base + lane] : 0;
    float el = (lane < cnt) ? csr_ea[base + lane] : 0.f;

    float a0[GAT_CHUNK], a1[GAT_CHUNK], ej[GAT_CHUNK];
    // broadcast + issue all gathers back-to-back (independent loads)
#pragma unroll
    for (int j = 0; j < GAT_CHUNK; j++) {
      if (j >= cnt) break;
      int s = __shfl(sl, j);
      ej[j] = __shfl(el, j);
      const float* row = xl + (size_t)s * 128;
      a0[j] = row[c0];
      a1[j] = row[c1];
    }
    // scores: independent shfl-reduce chains -> ILP
    float p0[GAT_CHUNK], p1[GAT_CHUNK];
#pragma unroll
    for (int j = 0; j < GAT_CHUNK; j++) {
      if (j >= cnt) break;
      float t0 = a0[j] + xr0 + ej[j] * we0;
      float t1 = a1[j] + xr1 + ej[j] * we1;
      t0 = (t0 >= 0.f) ? t0 : 0.2f * t0;  // leaky_relu
      t1 = (t1 >= 0.f) ? t1 : 0.2f * t1;
      float q0 = t0 * at0, q1 = t1 * at1;
#pragma unroll
      for (int off = 1; off < 16; off <<= 1) {
        q0 += __shfl_xor(q0, off);
        q1 += __shfl_xor(q1, off);
      }
      p0[j] = q0;
      p1[j] = q1;
    }
    // chunk max
    float cm0 = -INFINITY, cm1 = -INFINITY;
#pragma unroll
    for (int j = 0; j < GAT_CHUNK; j++) {
      if (j >= cnt) break;
      cm0 = fmaxf(cm0, p0[j]);
      cm1 = fmaxf(cm1, p1[j]);
    }
    float nm0 = fmaxf(m0, cm0);
    float nm1 = fmaxf(m1, cm1);
    float sc0 = __expf(m0 - nm0);  // exp(-inf)=0 on the first chunk
    float sc1 = __expf(m1 - nm1);
    d0 *= sc0;
    acc0 *= sc0;
    d1 *= sc1;
    acc1 *= sc1;
#pragma unroll
    for (int j = 0; j < GAT_CHUNK; j++) {
      if (j >= cnt) break;
      float e0 = __expf(p0[j] - nm0);
      float e1 = __expf(p1[j] - nm1);
      d0 += e0;
      acc0 += e0 * a0[j];
      d1 += e1;
      acc1 += e1 * a1[j];
    }
    m0 = nm0;
    m1 = nm1;
  }
  z[(size_t)v * 128 + c0] = acc0 / (d0 + 1e-16f) + bo_l[c0];
  z[(size_t)v * 128 + c1] = acc1 / (d1 + 1e-16f) + bo_l[c1];
}

// ---------------- BN: stats, finalize, apply ---------------------------------

__global__ __launch_bounds__(256) void bn_stats_kernel(const float* __restrict__ z,
                                                       float* __restrict__ stats, int n) {
  int c = threadIdx.x & 127;
  int half = threadIdx.x >> 7;
  int chunk = (n + gridDim.x - 1) / gridDim.x;
  int v0 = blockIdx.x * chunk;
  int v1 = min(v0 + chunk, n);
  float s = 0.f, q = 0.f;
  for (int v = v0 + half; v < v1; v += 2) {
    float val = z[(size_t)v * 128 + c];
    s += val;
    q += val * val;
  }
  __shared__ float ls[2][128], lq[2][128];
  ls[half][c] = s;
  lq[half][c] = q;
  __syncthreads();
  if (threadIdx.x < 128) {
    atomicAdd(&stats[c], ls[0][c] + ls[1][c]);
    atomicAdd(&stats[128 + c], lq[0][c] + lq[1][c]);
  }
}

__global__ __launch_bounds__(128) void bn_final_kernel(const float* __restrict__ stats,
                                                       const float* __restrict__ gamma_l,
                                                       const float* __restrict__ beta_l,
                                                       float* __restrict__ ss, int n) {
  int c = threadIdx.x;
  float mean = stats[c] / (float)n;
  float var = stats[128 + c] / (float)n - mean * mean;
  float rs = rsqrtf(var + 1e-5f);
  float sc = gamma_l[c] * rs;
  ss[c] = sc;
  ss[128 + c] = beta_l[c] - mean * sc;
}

__global__ __launch_bounds__(256) void bn_apply_kernel(const float* __restrict__ z,
                                                       const float* __restrict__ ss,
                                                       float* __restrict__ h, int add_res,
                                                       int n) {
  int idx = blockIdx.x * 256 + threadIdx.x;
  if (idx >= n * 128) return;
  int c = idx & 127;
  float val = z[idx] * ss[c] + ss[128 + c];
  if (add_res) val += h[idx];
  h[idx] = fmaxf(val, 0.f);
}

// ---------------- pooling, two-stage (batch = repeat(arange(B), N/B)) --------

#define POOL_SPLIT 8

__global__ __launch_bounds__(256) void pool_partial_kernel(const float* __restrict__ h,
                                                           float* __restrict__ part,
                                                           int npg) {
  int b = blockIdx.x, q = blockIdx.y;
  int half = threadIdx.x >> 7, c = threadIdx.x & 127;
  int rows = npg / POOL_SPLIT;
  const float* base = h + ((size_t)b * npg + q * rows) * 128;
  float s = 0.f;
  for (int r = half; r < rows; r += 2) s += base[(size_t)r * 128 + c];
  __shared__ float ls[2][128];
  ls[half][c] = s;
  __syncthreads();
  if (threadIdx.x < 128)
    part[((size_t)b * POOL_SPLIT + q) * 128 + c] = ls[0][c] + ls[1][c];
}

// ---------------- fused MLP head ---------------------------------------------

__global__ __launch_bounds__(128) void final_mlp_kernel(
    const float* __restrict__ part, float inv_npg, const float* __restrict__ gf,
    const float* __restrict__ mW1, const float* __restrict__ mb1,
    const float* __restrict__ mW2, const float* __restrict__ mb2,
    const float* __restrict__ gW1, const float* __restrict__ gb1,
    const float* __restrict__ gW2, const float* __restrict__ gb2,
    const float* __restrict__ fW1, const float* __restrict__ fb1,
    const float* __restrict__ fW2, const float* __restrict__ fb2,
    const float* __restrict__ fW3, const float* __restrict__ fb3,
    float* __restrict__ out) {
  int b = blockIdx.x, t = threadIdx.x;
  __shared__ float s1[16], s2[16], s1b[16], s2b[16];
  __shared__ float zv[160], t1[128], t2[64];

  if (t < 16) {
    float s = mb1[t];
    for (int i = 0; i < 4; i++) s += gf[b * 6 + i] * mW1[i * 16 + t];
    s1[t] = fmaxf(s, 0.f);
  } else if (t < 32) {
    int j = t - 16;
    float s = gb1[j];
    for (int i = 0; i < 2; i++) s += gf[b * 6 + 4 + i] * gW1[i * 16 + j];
    s2[j] = fmaxf(s, 0.f);
  }
  // pooled = mean over the graph = sum of the 8 partials / npg
  {
    float ps = 0.f;
#pragma unroll
    for (int q = 0; q < POOL_SPLIT; q++)
      ps += part[((size_t)b * POOL_SPLIT + q) * 128 + t];
    zv[t] = ps * inv_npg;
  }
  __syncthreads();
  if (t < 16) {
    float s = mb2[t];
    for (int i = 0; i < 16; i++) s += s1[i] * mW2[i * 16 + t];
    s1b[t] = fmaxf(s, 0.f);
  } else if (t < 32) {
    int j = t - 16;
    float s = gb2[j];
    for (int i = 0; i < 16; i++) s += s2[i] * gW2[i * 16 + j];
    s2b[j] = fmaxf(s, 0.f);
  }
  __syncthreads();
  if (t < 16)
    zv[128 + t] = s1b[t];
  else if (t < 32)
    zv[128 + t] = s2b[t - 16];
  __syncthreads();
  {
    float s = fb1[t];
    for (int i = 0; i < 160; i++) s += zv[i] * fW1[i * 128 + t];
    t1[t] = fmaxf(s, 0.f);
  }
  __syncthreads();
  if (t < 64) {
    float s = fb2[t];
    for (int i = 0; i < 128; i++) s += t1[i] * fW2[i * 64 + t];
    t2[t] = fmaxf(s, 0.f);
  }
  __syncthreads();
  if (t == 0) {
    float s = fb3[0];
    for (int i = 0; i < 64; i++) s += t2[i] * fW3[i];
    out[b] = s;
  }
}

// ---------------- host launcher ----------------------------------------------

extern "C" void kernel_launch(void* const* d_in, const int* in_sizes, int n_in,
                              void* d_out, int out_size, void* d_ws, size_t ws_size,
                              hipStream_t stream) {
  const float* x = (const float*)d_in[0];
  const int* ei = (const int*)d_in[1];
  const float* eattr = (const float*)d_in[2];
  // d_in[3] = batch: layout is repeat(arange(B), N/B); pooling exploits this.
  const float* gf = (const float*)d_in[4];
  const float* W_emb = (const float*)d_in[5];
  const float* b_emb = (const float*)d_in[6];
  const float* Wl1 = (const float*)d_in[7];
  const float* Wr1 = (const float*)d_in[8];
  const float* Wl234 = (const float*)d_in[9];
  const float* Wr234 = (const float*)d_in[10];
  const float* bl = (const float*)d_in[11];
  const float* br = (const float*)d_in[12];
  const float* We = (const float*)d_in[13];
  const float* att = (const float*)d_in[14];
  const float* bo = (const float*)d_in[15];
  const float* gamma = (const float*)d_in[16];
  const float* beta = (const float*)d_in[17];
  const float* mW1 = (const float*)d_in[18];
  const float* mb1 = (const float*)d_in[19];
  const float* mW2 = (const float*)d_in[20];
  const float* mb2 = (const float*)d_in[21];
  const float* gW1 = (const float*)d_in[22];
  const float* gb1 = (const float*)d_in[23];
  const float* gW2 = (const float*)d_in[24];
  const float* gb2 = (const float*)d_in[25];
  const float* fW1 = (const float*)d_in[26];
  const float* fb1 = (const float*)d_in[27];
  const float* fW2 = (const float*)d_in[28];
  const float* fb2 = (const float*)d_in[29];
  const float* fW3 = (const float*)d_in[30];
  const float* fb3 = (const float*)d_in[31];

  const int N = in_sizes[0] / 4;
  const int E = in_sizes[2];
  const int B = in_sizes[4] / 6;

  char* wsb = (char*)d_ws;
  size_t off = 0;
  auto alloc = [&](size_t bytes) {
    size_t r = off;
    off += (bytes + 255) & ~(size_t)255;
    return r;
  };
  float* h0 = (float*)(wsb + alloc((size_t)N * 64 * 4));
  float* h = (float*)(wsb + alloc((size_t)N * 128 * 4));
  float* xl = (float*)(wsb + alloc((size_t)N * 128 * 4));
  float* xr = (float*)(wsb + alloc((size_t)N * 128 * 4));
  float* z = (float*)(wsb + alloc((size_t)N * 128 * 4));
  int* csr_src = (int*)(wsb + alloc((size_t)(E + N) * 4));
  float* csr_ea = (float*)(wsb + alloc((size_t)(E + N) * 4));
  int* row_ofs = (int*)(wsb + alloc((size_t)(N + 1) * 4));
  int* cursor = (int*)(wsb + alloc((size_t)N * 4));
  int* deg = (int*)(wsb + alloc((size_t)N * 4));
  float* stats = (float*)(wsb + alloc(256 * 4));
  float* ss = (float*)(wsb + alloc(256 * 4));
  float* ea_sum = (float*)(wsb + alloc(256));
  float* part = (float*)(wsb + alloc((size_t)B * POOL_SPLIT * 128 * 4));
  (void)ws_size;
  (void)n_in;
  (void)out_size;

  // ---- CSR build ----
  hipMemsetAsync(ea_sum, 0, 4, stream);
  init_deg_kernel<<<(N + 255) / 256, 256, 0, stream>>>(deg, N);
  count_kernel<<<(E + 255) / 256, 256, 0, stream>>>(ei, eattr, deg, ea_sum, E);
  scan_kernel<<<1, 1024, 0, stream>>>(deg, row_ofs, N);
  copy_int_kernel<<<(N + 255) / 256, 256, 0, stream>>>(row_ofs, cursor, N);
  fill_kernel<<<(E + N + 255) / 256, 256, 0, stream>>>(ei, eattr, ea_sum, cursor,
                                                       csr_src, csr_ea, E, N);

  // ---- embed ----
  embed_kernel<<<(N * 64 + 255) / 256, 256, 0, stream>>>(x, W_emb, b_emb, h0, N);

  // ---- 4 GAT layers ----
  for (int L = 0; L < 4; ++L) {
    const float* in = (L == 0) ? h0 : h;
    int K = (L == 0) ? 64 : 128;
    const float* Wl_p = (L == 0) ? Wl1 : Wl234 + (size_t)(L - 1) * 128 * 128;
    const float* Wr_p = (L == 0) ? Wr1 : Wr234 + (size_t)(L - 1) * 128 * 128;

    gemm_kernel<<<dim3(N / 64, 2), 256, 0, stream>>>(in, K, Wl_p, Wr_p, bl + L * 128,
                                                     br + L * 128, xl, xr);
    gat_kernel<<<(N + 3) / 4, 256, 0, stream>>>(xl, xr, row_ofs, csr_src, csr_ea,
                                                We + L * 128, att + L * 128,
                                                bo + L * 128, z, N);
    hipMemsetAsync(stats, 0, 256 * 4, stream);
    bn_stats_kernel<<<256, 256, 0, stream>>>(z, stats, N);
    bn_final_kernel<<<1, 128, 0, stream>>>(stats, gamma + L * 128, beta + L * 128, ss, N);
    bn_apply_kernel<<<(N * 128 + 255) / 256, 256, 0, stream>>>(z, ss, h,
                                                               (L == 0) ? 0 : 1, N);
  }

  // ---- pool + head ----
  pool_partial_kernel<<<dim3(B, POOL_SPLIT), 256, 0, stream>>>(h, part, N / B);
  final_mlp_kernel<<<B, 128, 0, stream>>>(part, (float)B / (float)N, gf, mW1, mb1, mW2,
                                          mb2, gW1, gb1, gW2, gb2, fW1, fb1, fW2, fb2,
                                          fW3, fb3, (float*)d_out);
}

// Round 5
// 644.324 us; speedup vs baseline: 1.7362x; 1.7362x over previous
//
#include <hip/hip_runtime.h>
#include <cmath>

// ---------------------------------------------------------------------------
// BrainAgeGATv2: 4-layer GATv2-ish GNN, N=40000 nodes, E=400000 edges, B=100
// graphs, hidden = H*C = 128.
// R3: chunk-16 online-softmax gat PASSED but spilled (60 VGPR alloc vs ~100
//     live) -> 172 us/dispatch.
// R4: no-max softmax FAILED absmax (1.17e-2 vs 7.7e-3): bf16-rounded compare
//     needs the same exp(s - smax) ordering as the reference.
// R5: keep online max; kill the spill: float2 channel pairing (lane owns
//     channels 2l,2l+1, head = l/8 -> 1 dwordx2 gather/edge, 3-step shfl
//     reduce), chunk=8, launch_bounds(256,4). ~60 live VGPRs, no scratch.
// ---------------------------------------------------------------------------

// ---------------- preprocessing ----------------

__global__ __launch_bounds__(256) void init_deg_kernel(int* deg, int n) {
  int v = blockIdx.x * 256 + threadIdx.x;
  if (v < n) deg[v] = 1;  // self-loop
}

__global__ __launch_bounds__(256) void count_kernel(const int* __restrict__ ei,
                                                    const float* __restrict__ eattr,
                                                    int* deg, float* ea_sum, int E) {
  int e = blockIdx.x * 256 + threadIdx.x;
  float v = 0.f;
  if (e < E) {
    atomicAdd(&deg[ei[(size_t)E + e]], 1);  // dst = ei[1][e]
    v = eattr[e];
  }
  __shared__ float red[256];
  red[threadIdx.x] = v;
  __syncthreads();
  for (int off = 128; off > 0; off >>= 1) {
    if (threadIdx.x < off) red[threadIdx.x] += red[threadIdx.x + off];
    __syncthreads();
  }
  if (threadIdx.x == 0) atomicAdd(ea_sum, red[0]);
}

__global__ __launch_bounds__(1024) void scan_kernel(const int* __restrict__ deg,
                                                    int* row_ofs, int n) {
  __shared__ int partial[1024];
  int t = threadIdx.x;
  int per = (n + 1023) / 1024;
  int start = t * per;
  int end = min(start + per, n);
  int s = 0;
  for (int i = start; i < end; i++) s += deg[i];
  partial[t] = s;
  __syncthreads();
  for (int off = 1; off < 1024; off <<= 1) {
    int v = (t >= off) ? partial[t - off] : 0;
    __syncthreads();
    partial[t] += v;
    __syncthreads();
  }
  int run = (t == 0) ? 0 : partial[t - 1];
  for (int i = start; i < end; i++) {
    row_ofs[i] = run;
    run += deg[i];
  }
  if (t == 1023) row_ofs[n] = run;  // total = E + n
}

__global__ __launch_bounds__(256) void copy_int_kernel(const int* __restrict__ src,
                                                       int* __restrict__ dst, int n) {
  int i = blockIdx.x * 256 + threadIdx.x;
  if (i < n) dst[i] = src[i];
}

__global__ __launch_bounds__(256) void fill_kernel(const int* __restrict__ ei,
                                                   const float* __restrict__ eattr,
                                                   const float* __restrict__ ea_sum,
                                                   int* cursor, int* csr_src,
                                                   float* csr_ea, int E, int n) {
  int i = blockIdx.x * 256 + threadIdx.x;
  if (i >= E + n) return;
  int s, d;
  float ev;
  if (i < E) {
    s = ei[i];
    d = ei[(size_t)E + i];
    ev = eattr[i];
  } else {
    s = d = i - E;                       // self loop
    ev = ea_sum[0] * (1.0f / (float)E);  // mean(edge_attr)
  }
  int pos = atomicAdd(&cursor[d], 1);
  csr_src[pos] = s;
  csr_ea[pos] = ev;
}

// ---------------- embed: h0 = relu(x @ W_emb + b_emb), x: N x 4, W: 4 x 64 ----

__global__ __launch_bounds__(256) void embed_kernel(const float* __restrict__ x,
                                                    const float* __restrict__ W,
                                                    const float* __restrict__ bvec,
                                                    float* __restrict__ h0, int n) {
  int idx = blockIdx.x * 256 + threadIdx.x;
  if (idx >= n * 64) return;
  int v = idx >> 6, j = idx & 63;
  float s = bvec[j];
  s += x[v * 4 + 0] * W[j];
  s += x[v * 4 + 1] * W[64 + j];
  s += x[v * 4 + 2] * W[128 + j];
  s += x[v * 4 + 3] * W[192 + j];
  h0[idx] = fmaxf(s, 0.f);
}

// ---------------- GEMM: out = in(N x K) @ W(K x 128) + bias; two W per launch --

__global__ __launch_bounds__(256) void gemm_kernel(const float* __restrict__ in, int K,
                                                   const float* __restrict__ W0,
                                                   const float* __restrict__ W1,
                                                   const float* __restrict__ b0,
                                                   const float* __restrict__ b1,
                                                   float* __restrict__ o0,
                                                   float* __restrict__ o1) {
  const float* W = blockIdx.y ? W1 : W0;
  const float* bias = blockIdx.y ? b1 : b0;
  float* out = blockIdx.y ? o1 : o0;

  __shared__ float hs[64][33];    // 64 rows x 32 k (+1 pad)
  __shared__ float wsm[32][128];  // 32 k x 128 cols

  int t = threadIdx.x;
  int r0 = blockIdx.x * 64;
  int tc = t & 15;  // col-thread: cols tc*8 .. +8
  int tr = t >> 4;  // row-thread: rows tr*4 .. +4

  float acc[4][8];
#pragma unroll
  for (int i = 0; i < 4; i++)
#pragma unroll
    for (int j = 0; j < 8; j++) acc[i][j] = 0.f;

  for (int k0 = 0; k0 < K; k0 += 32) {
// stage in-tile: 64x32 floats (512 float4, 2 per thread)
#pragma unroll
    for (int i = 0; i < 2; i++) {
      int f = t * 2 + i;  // 0..511
      int row = f >> 3;
      int kk = (f & 7) * 4;
      float4 v = *reinterpret_cast<const float4*>(in + (size_t)(r0 + row) * K + k0 + kk);
      hs[row][kk + 0] = v.x;
      hs[row][kk + 1] = v.y;
      hs[row][kk + 2] = v.z;
      hs[row][kk + 3] = v.w;
    }
// stage W-tile: 32x128 floats (1024 float4, 4 per thread)
#pragma unroll
    for (int i = 0; i < 4; i++) {
      int f = t * 4 + i;  // 0..1023
      int kk = f >> 5;
      int c4 = (f & 31) * 4;
      *reinterpret_cast<float4*>(&wsm[kk][c4]) =
          *reinterpret_cast<const float4*>(W + (size_t)(k0 + kk) * 128 + c4);
    }
    __syncthreads();
#pragma unroll 4
    for (int kk = 0; kk < 32; kk++) {
      float a0 = hs[tr * 4 + 0][kk];
      float a1 = hs[tr * 4 + 1][kk];
      float a2 = hs[tr * 4 + 2][kk];
      float a3 = hs[tr * 4 + 3][kk];
      float4 bb0 = *reinterpret_cast<float4*>(&wsm[kk][tc * 8]);
      float4 bb1 = *reinterpret_cast<float4*>(&wsm[kk][tc * 8 + 4]);
      float bv[8] = {bb0.x, bb0.y, bb0.z, bb0.w, bb1.x, bb1.y, bb1.z, bb1.w};
#pragma unroll
      for (int j = 0; j < 8; j++) {
        acc[0][j] += a0 * bv[j];
        acc[1][j] += a1 * bv[j];
        acc[2][j] += a2 * bv[j];
        acc[3][j] += a3 * bv[j];
      }
    }
    __syncthreads();
  }
#pragma unroll
  for (int i = 0; i < 4; i++) {
    int r = r0 + tr * 4 + i;
#pragma unroll
    for (int j = 0; j < 8; j++) {
      out[(size_t)r * 128 + tc * 8 + j] = acc[i][j] + bias[tc * 8 + j];
    }
  }
}

// ---------------- GAT aggregation: wave per node, chunked online softmax -----
// Lane owns channels (2l, 2l+1), both in head l/8: one dwordx2 gather per
// edge, 3-step shfl head-reduce. Chunk of 8 edges gathered back-to-back
// (MLP), per-chunk max + single rescale (exact exp(s - smax) semantics).

#define GAT_CHUNK 8

__global__ __launch_bounds__(256, 4) void gat_kernel(
    const float* __restrict__ xl, const float* __restrict__ xr,
    const int* __restrict__ row_ofs, const int* __restrict__ csr_src,
    const float* __restrict__ csr_ea, const float* __restrict__ We_l,
    const float* __restrict__ att_l, const float* __restrict__ bo_l,
    float* __restrict__ z, int n) {
  int wave = threadIdx.x >> 6;
  int lane = threadIdx.x & 63;
  int v = blockIdx.x * 4 + wave;
  if (v >= n) return;

  int c = lane * 2;  // channels c, c+1; head = c/16 = lane/8
  float2 xrv = *reinterpret_cast<const float2*>(xr + (size_t)v * 128 + c);
  float2 wev = *reinterpret_cast<const float2*>(We_l + c);
  float2 atv = *reinterpret_cast<const float2*>(att_l + c);

  float m = -INFINITY, d = 0.f;
  float acc0 = 0.f, acc1 = 0.f;

  int beg = row_ofs[v], end = row_ofs[v + 1];
  for (int base = beg; base < end; base += GAT_CHUNK) {
    int cnt = min(GAT_CHUNK, end - base);
    // lane-parallel metadata load (lanes 0..cnt-1), wave-uniform cnt
    int sl = (lane < cnt) ? csr_src[base + lane] : 0;
    float el = (lane < cnt) ? csr_ea[base + lane] : 0.f;

    float2 a[GAT_CHUNK];
    float ee[GAT_CHUNK];
    // broadcast + issue all gathers back-to-back (independent dwordx2 loads)
#pragma unroll
    for (int j = 0; j < GAT_CHUNK; j++) {
      if (j >= cnt) break;
      int s = __shfl(sl, j);
      ee[j] = __shfl(el, j);
      a[j] = *reinterpret_cast<const float2*>(xl + (size_t)s * 128 + c);
    }
    // scores: leaky_relu -> att dot -> 8-lane head reduce (3 shfl steps)
    float q[GAT_CHUNK];
#pragma unroll
    for (int j = 0; j < GAT_CHUNK; j++) {
      if (j >= cnt) break;
      float t0 = a[j].x + xrv.x + ee[j] * wev.x;
      float t1 = a[j].y + xrv.y + ee[j] * wev.y;
      t0 = (t0 >= 0.f) ? t0 : 0.2f * t0;  // leaky_relu
      t1 = (t1 >= 0.f) ? t1 : 0.2f * t1;
      float qq = t0 * atv.x + t1 * atv.y;
#pragma unroll
      for (int off = 1; off < 8; off <<= 1) qq += __shfl_xor(qq, off);
      q[j] = qq;
    }
    // chunk max + single rescale
    float cm = -INFINITY;
#pragma unroll
    for (int j = 0; j < GAT_CHUNK; j++) {
      if (j >= cnt) break;
      cm = fmaxf(cm, q[j]);
    }
    float nm = fmaxf(m, cm);
    float sc = __expf(m - nm);  // exp(-inf)=0 on the first chunk
    d *= sc;
    acc0 *= sc;
    acc1 *= sc;
#pragma unroll
    for (int j = 0; j < GAT_CHUNK; j++) {
      if (j >= cnt) break;
      float e = __expf(q[j] - nm);
      d += e;
      acc0 += e * a[j].x;
      acc1 += e * a[j].y;
    }
    m = nm;
  }
  float inv = 1.f / (d + 1e-16f);
  float2 o;
  o.x = acc0 * inv + bo_l[c];
  o.y = acc1 * inv + bo_l[c + 1];
  *reinterpret_cast<float2*>(z + (size_t)v * 128 + c) = o;
}

// ---------------- BN: stats, finalize, apply ---------------------------------

__global__ __launch_bounds__(256) void bn_stats_kernel(const float* __restrict__ z,
                                                       float* __restrict__ stats, int n) {
  int c = threadIdx.x & 127;
  int half = threadIdx.x >> 7;
  int chunk = (n + gridDim.x - 1) / gridDim.x;
  int v0 = blockIdx.x * chunk;
  int v1 = min(v0 + chunk, n);
  float s = 0.f, q = 0.f;
  for (int v = v0 + half; v < v1; v += 2) {
    float val = z[(size_t)v * 128 + c];
    s += val;
    q += val * val;
  }
  __shared__ float ls[2][128], lq[2][128];
  ls[half][c] = s;
  lq[half][c] = q;
  __syncthreads();
  if (threadIdx.x < 128) {
    atomicAdd(&stats[c], ls[0][c] + ls[1][c]);
    atomicAdd(&stats[128 + c], lq[0][c] + lq[1][c]);
  }
}

__global__ __launch_bounds__(128) void bn_final_kernel(const float* __restrict__ stats,
                                                       const float* __restrict__ gamma_l,
                                                       const float* __restrict__ beta_l,
                                                       float* __restrict__ ss, int n) {
  int c = threadIdx.x;
  float mean = stats[c] / (float)n;
  float var = stats[128 + c] / (float)n - mean * mean;
  float rs = rsqrtf(var + 1e-5f);
  float sc = gamma_l[c] * rs;
  ss[c] = sc;
  ss[128 + c] = beta_l[c] - mean * sc;
}

__global__ __launch_bounds__(256) void bn_apply_kernel(const float* __restrict__ z,
                                                       const float* __restrict__ ss,
                                                       float* __restrict__ h, int add_res,
                                                       int n) {
  int idx = blockIdx.x * 256 + threadIdx.x;
  if (idx >= n * 128) return;
  int c = idx & 127;
  float val = z[idx] * ss[c] + ss[128 + c];
  if (add_res) val += h[idx];
  h[idx] = fmaxf(val, 0.f);
}

// ---------------- pooling, two-stage (batch = repeat(arange(B), N/B)) --------

#define POOL_SPLIT 8

__global__ __launch_bounds__(256) void pool_partial_kernel(const float* __restrict__ h,
                                                           float* __restrict__ part,
                                                           int npg) {
  int b = blockIdx.x, q = blockIdx.y;
  int half = threadIdx.x >> 7, c = threadIdx.x & 127;
  int rows = npg / POOL_SPLIT;
  const float* base = h + ((size_t)b * npg + q * rows) * 128;
  float s = 0.f;
  for (int r = half; r < rows; r += 2) s += base[(size_t)r * 128 + c];
  __shared__ float ls[2][128];
  ls[half][c] = s;
  __syncthreads();
  if (threadIdx.x < 128)
    part[((size_t)b * POOL_SPLIT + q) * 128 + c] = ls[0][c] + ls[1][c];
}

// ---------------- fused MLP head ---------------------------------------------

__global__ __launch_bounds__(128) void final_mlp_kernel(
    const float* __restrict__ part, float inv_npg, const float* __restrict__ gf,
    const float* __restrict__ mW1, const float* __restrict__ mb1,
    const float* __restrict__ mW2, const float* __restrict__ mb2,
    const float* __restrict__ gW1, const float* __restrict__ gb1,
    const float* __restrict__ gW2, const float* __restrict__ gb2,
    const float* __restrict__ fW1, const float* __restrict__ fb1,
    const float* __restrict__ fW2, const float* __restrict__ fb2,
    const float* __restrict__ fW3, const float* __restrict__ fb3,
    float* __restrict__ out) {
  int b = blockIdx.x, t = threadIdx.x;
  __shared__ float s1[16], s2[16], s1b[16], s2b[16];
  __shared__ float zv[160], t1[128], t2[64];

  if (t < 16) {
    float s = mb1[t];
    for (int i = 0; i < 4; i++) s += gf[b * 6 + i] * mW1[i * 16 + t];
    s1[t] = fmaxf(s, 0.f);
  } else if (t < 32) {
    int j = t - 16;
    float s = gb1[j];
    for (int i = 0; i < 2; i++) s += gf[b * 6 + 4 + i] * gW1[i * 16 + j];
    s2[j] = fmaxf(s, 0.f);
  }
  // pooled = mean over the graph = sum of the 8 partials / npg
  {
    float ps = 0.f;
#pragma unroll
    for (int q = 0; q < POOL_SPLIT; q++)
      ps += part[((size_t)b * POOL_SPLIT + q) * 128 + t];
    zv[t] = ps * inv_npg;
  }
  __syncthreads();
  if (t < 16) {
    float s = mb2[t];
    for (int i = 0; i < 16; i++) s += s1[i] * mW2[i * 16 + t];
    s1b[t] = fmaxf(s, 0.f);
  } else if (t < 32) {
    int j = t - 16;
    float s = gb2[j];
    for (int i = 0; i < 16; i++) s += s2[i] * gW2[i * 16 + j];
    s2b[j] = fmaxf(s, 0.f);
  }
  __syncthreads();
  if (t < 16)
    zv[128 + t] = s1b[t];
  else if (t < 32)
    zv[128 + t] = s2b[t - 16];
  __syncthreads();
  {
    float s = fb1[t];
    for (int i = 0; i < 160; i++) s += zv[i] * fW1[i * 128 + t];
    t1[t] = fmaxf(s, 0.f);
  }
  __syncthreads();
  if (t < 64) {
    float s = fb2[t];
    for (int i = 0; i < 128; i++) s += t1[i] * fW2[i * 64 + t];
    t2[t] = fmaxf(s, 0.f);
  }
  __syncthreads();
  if (t == 0) {
    float s = fb3[0];
    for (int i = 0; i < 64; i++) s += t2[i] * fW3[i];
    out[b] = s;
  }
}

// ---------------- host launcher ----------------------------------------------

extern "C" void kernel_launch(void* const* d_in, const int* in_sizes, int n_in,
                              void* d_out, int out_size, void* d_ws, size_t ws_size,
                              hipStream_t stream) {
  const float* x = (const float*)d_in[0];
  const int* ei = (const int*)d_in[1];
  const float* eattr = (const float*)d_in[2];
  // d_in[3] = batch: layout is repeat(arange(B), N/B); pooling exploits this.
  const float* gf = (const float*)d_in[4];
  const float* W_emb = (const float*)d_in[5];
  const float* b_emb = (const float*)d_in[6];
  const float* Wl1 = (const float*)d_in[7];
  const float* Wr1 = (const float*)d_in[8];
  const float* Wl234 = (const float*)d_in[9];
  const float* Wr234 = (const float*)d_in[10];
  const float* bl = (const float*)d_in[11];
  const float* br = (const float*)d_in[12];
  const float* We = (const float*)d_in[13];
  const float* att = (const float*)d_in[14];
  const float* bo = (const float*)d_in[15];
  const float* gamma = (const float*)d_in[16];
  const float* beta = (const float*)d_in[17];
  const float* mW1 = (const float*)d_in[18];
  const float* mb1 = (const float*)d_in[19];
  const float* mW2 = (const float*)d_in[20];
  const float* mb2 = (const float*)d_in[21];
  const float* gW1 = (const float*)d_in[22];
  const float* gb1 = (const float*)d_in[23];
  const float* gW2 = (const float*)d_in[24];
  const float* gb2 = (const float*)d_in[25];
  const float* fW1 = (const float*)d_in[26];
  const float* fb1 = (const float*)d_in[27];
  const float* fW2 = (const float*)d_in[28];
  const float* fb2 = (const float*)d_in[29];
  const float* fW3 = (const float*)d_in[30];
  const float* fb3 = (const float*)d_in[31];

  const int N = in_sizes[0] / 4;
  const int E = in_sizes[2];
  const int B = in_sizes[4] / 6;

  char* wsb = (char*)d_ws;
  size_t off = 0;
  auto alloc = [&](size_t bytes) {
    size_t r = off;
    off += (bytes + 255) & ~(size_t)255;
    return r;
  };
  float* h0 = (float*)(wsb + alloc((size_t)N * 64 * 4));
  float* h = (float*)(wsb + alloc((size_t)N * 128 * 4));
  float* xl = (float*)(wsb + alloc((size_t)N * 128 * 4));
  float* xr = (float*)(wsb + alloc((size_t)N * 128 * 4));
  float* z = (float*)(wsb + alloc((size_t)N * 128 * 4));
  int* csr_src = (int*)(wsb + alloc((size_t)(E + N) * 4));
  float* csr_ea = (float*)(wsb + alloc((size_t)(E + N) * 4));
  int* row_ofs = (int*)(wsb + alloc((size_t)(N + 1) * 4));
  int* cursor = (int*)(wsb + alloc((size_t)N * 4));
  int* deg = (int*)(wsb + alloc((size_t)N * 4));
  float* stats = (float*)(wsb + alloc(256 * 4));
  float* ss = (float*)(wsb + alloc(256 * 4));
  float* ea_sum = (float*)(wsb + alloc(256));
  float* part = (float*)(wsb + alloc((size_t)B * POOL_SPLIT * 128 * 4));
  (void)ws_size;
  (void)n_in;
  (void)out_size;

  // ---- CSR build ----
  hipMemsetAsync(ea_sum, 0, 4, stream);
  init_deg_kernel<<<(N + 255) / 256, 256, 0, stream>>>(deg, N);
  count_kernel<<<(E + 255) / 256, 256, 0, stream>>>(ei, eattr, deg, ea_sum, E);
  scan_kernel<<<1, 1024, 0, stream>>>(deg, row_ofs, N);
  copy_int_kernel<<<(N + 255) / 256, 256, 0, stream>>>(row_ofs, cursor, N);
  fill_kernel<<<(E + N + 255) / 256, 256, 0, stream>>>(ei, eattr, ea_sum, cursor,
                                                       csr_src, csr_ea, E, N);

  // ---- embed ----
  embed_kernel<<<(N * 64 + 255) / 256, 256, 0, stream>>>(x, W_emb, b_emb, h0, N);

  // ---- 4 GAT layers ----
  for (int L = 0; L < 4; ++L) {
    const float* in = (L == 0) ? h0 : h;
    int K = (L == 0) ? 64 : 128;
    const float* Wl_p = (L == 0) ? Wl1 : Wl234 + (size_t)(L - 1) * 128 * 128;
    const float* Wr_p = (L == 0) ? Wr1 : Wr234 + (size_t)(L - 1) * 128 * 128;

    gemm_kernel<<<dim3(N / 64, 2), 256, 0, stream>>>(in, K, Wl_p, Wr_p, bl + L * 128,
                                                     br + L * 128, xl, xr);
    gat_kernel<<<(N + 3) / 4, 256, 0, stream>>>(xl, xr, row_ofs, csr_src, csr_ea,
                                                We + L * 128, att + L * 128,
                                                bo + L * 128, z, N);
    hipMemsetAsync(stats, 0, 256 * 4, stream);
    bn_stats_kernel<<<256, 256, 0, stream>>>(z, stats, N);
    bn_final_kernel<<<1, 128, 0, stream>>>(stats, gamma + L * 128, beta + L * 128, ss, N);
    bn_apply_kernel<<<(N * 128 + 255) / 256, 256, 0, stream>>>(z, ss, h,
                                                               (L == 0) ? 0 : 1, N);
  }

  // ---- pool + head ----
  pool_partial_kernel<<<dim3(B, POOL_SPLIT), 256, 0, stream>>>(h, part, N / B);
  final_mlp_kernel<<<B, 128, 0, stream>>>(part, (float)B / (float)N, gf, mW1, mb1, mW2,
                                          mb2, gW1, gb1, gW2, gb2, fW1, fb1, fW2, fb2,
                                          fW3, fb3, (float*)d_out);
}

// Round 6
// 545.015 us; speedup vs baseline: 2.0525x; 1.1822x over previous
//
#include <hip/hip_runtime.h>
#include <cmath>

// ---------------------------------------------------------------------------
// BrainAgeGATv2: 4-layer GATv2-ish GNN, N=40000 nodes, E=400000 edges, B=100
// graphs, hidden = H*C = 128.
// R5: float2-paired gat (passed, 644 us). Top dispatch became scan_kernel
//     (single-block, 65 us).
// R6: (1) multi-block scan (3 small kernels, ~5 us total).
//     (2) GEMM -> MFMA split-bf16: xlr = h @ [Wl|Wr] via 16x16x32 bf16 mfma,
//         3-term split (hi*hi + hi*lo + lo*hi, ~1e-6 rel err == fp32 drift).
//         h hi/lo emitted free by bn_apply/embed; W split+transposed per
//         layer by a tiny kernel. LDS XOR-swizzled, one barrier per block.
// ---------------------------------------------------------------------------

typedef __bf16 bf16x8 __attribute__((ext_vector_type(8)));
typedef float f32x4 __attribute__((ext_vector_type(4)));

// ---------------- preprocessing ----------------

__global__ __launch_bounds__(256) void init_deg_kernel(int* deg, int n) {
  int v = blockIdx.x * 256 + threadIdx.x;
  if (v < n) deg[v] = 1;  // self-loop
}

__global__ __launch_bounds__(256) void count_kernel(const int* __restrict__ ei,
                                                    const float* __restrict__ eattr,
                                                    int* deg, float* ea_sum, int E) {
  int e = blockIdx.x * 256 + threadIdx.x;
  float v = 0.f;
  if (e < E) {
    atomicAdd(&deg[ei[(size_t)E + e]], 1);  // dst = ei[1][e]
    v = eattr[e];
  }
  __shared__ float red[256];
  red[threadIdx.x] = v;
  __syncthreads();
  for (int off = 128; off > 0; off >>= 1) {
    if (threadIdx.x < off) red[threadIdx.x] += red[threadIdx.x + off];
    __syncthreads();
  }
  if (threadIdx.x == 0) atomicAdd(ea_sum, red[0]);
}

// ---- multi-block exclusive scan of deg -> row_ofs (replaces 65us 1-block) ---

__global__ __launch_bounds__(256) void block_sum_kernel(const int* __restrict__ deg,
                                                        int* __restrict__ bsum, int n) {
  int i = blockIdx.x * 256 + threadIdx.x;
  int v = (i < n) ? deg[i] : 0;
  __shared__ int s[256];
  s[threadIdx.x] = v;
  __syncthreads();
  for (int off = 128; off > 0; off >>= 1) {
    if (threadIdx.x < off) s[threadIdx.x] += s[threadIdx.x + off];
    __syncthreads();
  }
  if (threadIdx.x == 0) bsum[blockIdx.x] = s[0];
}

__global__ __launch_bounds__(256) void scan_sums_kernel(const int* __restrict__ bsum,
                                                        int* __restrict__ bofs, int G) {
  int t = threadIdx.x;
  int v = (t < G) ? bsum[t] : 0;
  __shared__ int s[256];
  s[t] = v;
  __syncthreads();
  for (int off = 1; off < 256; off <<= 1) {
    int x = (t >= off) ? s[t - off] : 0;
    __syncthreads();
    s[t] += x;
    __syncthreads();
  }
  if (t < G) bofs[t] = s[t] - v;  // exclusive
}

__global__ __launch_bounds__(256) void write_ofs_kernel(const int* __restrict__ deg,
                                                        const int* __restrict__ bofs,
                                                        int* __restrict__ row_ofs, int n) {
  int t = threadIdx.x;
  int i = blockIdx.x * 256 + t;
  int d = (i < n) ? deg[i] : 0;
  __shared__ int s[256];
  s[t] = d;
  __syncthreads();
  for (int off = 1; off < 256; off <<= 1) {
    int x = (t >= off) ? s[t - off] : 0;
    __syncthreads();
    s[t] += x;
    __syncthreads();
  }
  int ofs = bofs[blockIdx.x] + s[t] - d;  // exclusive prefix
  if (i < n) row_ofs[i] = ofs;
  if (i == n - 1) row_ofs[n] = ofs + d;
}

__global__ __launch_bounds__(256) void copy_int_kernel(const int* __restrict__ src,
                                                       int* __restrict__ dst, int n) {
  int i = blockIdx.x * 256 + threadIdx.x;
  if (i < n) dst[i] = src[i];
}

__global__ __launch_bounds__(256) void fill_kernel(const int* __restrict__ ei,
                                                   const float* __restrict__ eattr,
                                                   const float* __restrict__ ea_sum,
                                                   int* cursor, int* csr_src,
                                                   float* csr_ea, int E, int n) {
  int i = blockIdx.x * 256 + threadIdx.x;
  if (i >= E + n) return;
  int s, d;
  float ev;
  if (i < E) {
    s = ei[i];
    d = ei[(size_t)E + i];
    ev = eattr[i];
  } else {
    s = d = i - E;                       // self loop
    ev = ea_sum[0] * (1.0f / (float)E);  // mean(edge_attr)
  }
  int pos = atomicAdd(&cursor[d], 1);
  csr_src[pos] = s;
  csr_ea[pos] = ev;
}

// ---------------- embed: h0 = relu(x @ W_emb + b_emb) -> bf16 hi/lo splits ---

__global__ __launch_bounds__(256) void embed_kernel(const float* __restrict__ x,
                                                    const float* __restrict__ W,
                                                    const float* __restrict__ bvec,
                                                    __bf16* __restrict__ hhi,
                                                    __bf16* __restrict__ hlo, int n) {
  int idx = blockIdx.x * 256 + threadIdx.x;
  if (idx >= n * 64) return;
  int v = idx >> 6, j = idx & 63;
  float s = bvec[j];
  s += x[v * 4 + 0] * W[j];
  s += x[v * 4 + 1] * W[64 + j];
  s += x[v * 4 + 2] * W[128 + j];
  s += x[v * 4 + 3] * W[192 + j];
  s = fmaxf(s, 0.f);
  __bf16 hi = (__bf16)s;
  hhi[idx] = hi;
  hlo[idx] = (__bf16)(s - (float)hi);
}

// ---------------- W split: wt[j][k] = split of [Wl|Wr][k][j] (transposed) ----

__global__ __launch_bounds__(256) void w_split_kernel(const float* __restrict__ Wl,
                                                      const float* __restrict__ Wr,
                                                      __bf16* __restrict__ wtHi,
                                                      __bf16* __restrict__ wtLo, int K) {
  int k = blockIdx.x;  // 0..K-1
  int j = threadIdx.x; // 0..255
  float v = (j < 128) ? Wl[k * 128 + j] : Wr[k * 128 + (j - 128)];
  __bf16 hi = (__bf16)v;
  wtHi[(size_t)j * K + k] = hi;
  wtLo[(size_t)j * K + k] = (__bf16)(v - (float)hi);
}

// ---------------- MFMA GEMM: xlr[M][256] = h[M][K] @ [Wl|Wr] + bias ----------
// Split-bf16 (3 terms). Block: 64M x 64N, 4 waves (wave w = rows 16w..16w+15,
// all 64 N as 4 subtiles). Full-K LDS tiles (A hi/lo + Wt hi/lo = 64 KB),
// XOR-swizzle byte^=(row&7)<<4 for conflict-free ds_read_b128.
// Fragment mapping (m89/m101-verified): a: lane l -> A[l%16][8*(l>>4)+e];
// b: lane l -> B[8*(l>>4)+e][l%16] (Wt stored [col][K] row-major);
// d: lane l, reg r -> D[4*(l>>4)+r][l%16].

__global__ __launch_bounds__(256) void gemm_mfma_kernel(
    const __bf16* __restrict__ hA, const __bf16* __restrict__ lA,
    const __bf16* __restrict__ wtHi, const __bf16* __restrict__ wtLo,
    const float* __restrict__ bl_l, const float* __restrict__ br_l,
    float* __restrict__ xlr, int K) {
  __shared__ uint4 ldsAhiV[1024], ldsAloV[1024], ldsWhiV[1024], ldsWloV[1024];
  char* pAhi = (char*)ldsAhiV;
  char* pAlo = (char*)ldsAloV;
  char* pWhi = (char*)ldsWhiV;
  char* pWlo = (char*)ldsWloV;

  int t = threadIdx.x;
  int n0 = blockIdx.x * 64;  // N-tile (grid.x = 4 -> consecutive blocks share A)
  int r0 = blockIdx.y * 64;  // M-tile
  int rs = K << 1;           // LDS row stride bytes

  // stage A (64 x K) hi/lo and Wt (64 x K) hi/lo, 16B units
  int units = (K == 128) ? 1024 : 512;
  for (int uu = t; uu < units; uu += 256) {
    int row, u;
    if (K == 128) { row = uu >> 4; u = uu & 15; }
    else          { row = uu >> 3; u = uu & 7; }
    int lb = row * rs + (u << 4);
    lb ^= (row & 7) << 4;
    size_t ga = (size_t)(r0 + row) * K;
    *(uint4*)(pAhi + lb) = ((const uint4*)(hA + ga))[u];
    *(uint4*)(pAlo + lb) = ((const uint4*)(lA + ga))[u];
    size_t gw = (size_t)(n0 + row) * K;
    *(uint4*)(pWhi + lb) = ((const uint4*)(wtHi + gw))[u];
    *(uint4*)(pWlo + lb) = ((const uint4*)(wtLo + gw))[u];
  }
  __syncthreads();

  int w = t >> 6, lane = t & 63;
  int arow = (w << 4) + (lane & 15);
  int kbb = (lane >> 4) << 4;  // k-group byte offset within 32-k step

  f32x4 acc[4];
#pragma unroll
  for (int n = 0; n < 4; n++) acc[n] = (f32x4){0.f, 0.f, 0.f, 0.f};

  union U { uint4 u; bf16x8 b; };
  for (int ks = 0; ks < K; ks += 32) {
    int kbyte = (ks << 1) + kbb;
    int ab = arow * rs + kbyte;
    ab ^= (arow & 7) << 4;
    U ahi, alo;
    ahi.u = *(const uint4*)(pAhi + ab);
    alo.u = *(const uint4*)(pAlo + ab);
#pragma unroll
    for (int n = 0; n < 4; n++) {
      int brow = (n << 4) + (lane & 15);
      int bb = brow * rs + kbyte;
      bb ^= (brow & 7) << 4;
      U bhi, blo;
      bhi.u = *(const uint4*)(pWhi + bb);
      blo.u = *(const uint4*)(pWlo + bb);
      acc[n] = __builtin_amdgcn_mfma_f32_16x16x32_bf16(ahi.b, bhi.b, acc[n], 0, 0, 0);
      acc[n] = __builtin_amdgcn_mfma_f32_16x16x32_bf16(ahi.b, blo.b, acc[n], 0, 0, 0);
      acc[n] = __builtin_amdgcn_mfma_f32_16x16x32_bf16(alo.b, bhi.b, acc[n], 0, 0, 0);
    }
  }

#pragma unroll
  for (int n = 0; n < 4; n++) {
    int col = n0 + (n << 4) + (lane & 15);
    float bv = (n0 < 128) ? bl_l[col & 127] : br_l[col & 127];
#pragma unroll
    for (int r = 0; r < 4; r++) {
      int row = r0 + (w << 4) + ((lane >> 4) << 2) + r;
      xlr[(size_t)row * 256 + col] = acc[n][r] + bv;
    }
  }
}

// ---------------- GAT aggregation (R5 structure, xlr layout) -----------------

#define GAT_CHUNK 8

__global__ __launch_bounds__(256, 4) void gat_kernel(
    const float* __restrict__ xlr, const int* __restrict__ row_ofs,
    const int* __restrict__ csr_src, const float* __restrict__ csr_ea,
    const float* __restrict__ We_l, const float* __restrict__ att_l,
    const float* __restrict__ bo_l, float* __restrict__ z, int n) {
  int wave = threadIdx.x >> 6;
  int lane = threadIdx.x & 63;
  int v = blockIdx.x * 4 + wave;
  if (v >= n) return;

  int c = lane * 2;  // channels c, c+1; head = c/16 = lane/8
  float2 xrv = *reinterpret_cast<const float2*>(xlr + (size_t)v * 256 + 128 + c);
  float2 wev = *reinterpret_cast<const float2*>(We_l + c);
  float2 atv = *reinterpret_cast<const float2*>(att_l + c);

  float m = -INFINITY, d = 0.f;
  float acc0 = 0.f, acc1 = 0.f;

  int beg = row_ofs[v], end = row_ofs[v + 1];
  for (int base = beg; base < end; base += GAT_CHUNK) {
    int cnt = min(GAT_CHUNK, end - base);
    int sl = (lane < cnt) ? csr_src[base + lane] : 0;
    float el = (lane < cnt) ? csr_ea[base + lane] : 0.f;

    float2 a[GAT_CHUNK];
    float ee[GAT_CHUNK];
#pragma unroll
    for (int j = 0; j < GAT_CHUNK; j++) {
      if (j >= cnt) break;
      int s = __shfl(sl, j);
      ee[j] = __shfl(el, j);
      a[j] = *reinterpret_cast<const float2*>(xlr + (size_t)s * 256 + c);
    }
    float q[GAT_CHUNK];
#pragma unroll
    for (int j = 0; j < GAT_CHUNK; j++) {
      if (j >= cnt) break;
      float t0 = a[j].x + xrv.x + ee[j] * wev.x;
      float t1 = a[j].y + xrv.y + ee[j] * wev.y;
      t0 = (t0 >= 0.f) ? t0 : 0.2f * t0;  // leaky_relu
      t1 = (t1 >= 0.f) ? t1 : 0.2f * t1;
      float qq = t0 * atv.x + t1 * atv.y;
#pragma unroll
      for (int off = 1; off < 8; off <<= 1) qq += __shfl_xor(qq, off);
      q[j] = qq;
    }
    float cm = -INFINITY;
#pragma unroll
    for (int j = 0; j < GAT_CHUNK; j++) {
      if (j >= cnt) break;
      cm = fmaxf(cm, q[j]);
    }
    float nm = fmaxf(m, cm);
    float sc = __expf(m - nm);
    d *= sc;
    acc0 *= sc;
    acc1 *= sc;
#pragma unroll
    for (int j = 0; j < GAT_CHUNK; j++) {
      if (j >= cnt) break;
      float e = __expf(q[j] - nm);
      d += e;
      acc0 += e * a[j].x;
      acc1 += e * a[j].y;
    }
    m = nm;
  }
  float inv = 1.f / (d + 1e-16f);
  float2 o;
  o.x = acc0 * inv + bo_l[c];
  o.y = acc1 * inv + bo_l[c + 1];
  *reinterpret_cast<float2*>(z + (size_t)v * 128 + c) = o;
}

// ---------------- BN: stats, finalize, apply (+ bf16 split emit) -------------

__global__ __launch_bounds__(256) void bn_stats_kernel(const float* __restrict__ z,
                                                       float* __restrict__ stats, int n) {
  int c = threadIdx.x & 127;
  int half = threadIdx.x >> 7;
  int chunk = (n + gridDim.x - 1) / gridDim.x;
  int v0 = blockIdx.x * chunk;
  int v1 = min(v0 + chunk, n);
  float s = 0.f, q = 0.f;
  for (int v = v0 + half; v < v1; v += 2) {
    float val = z[(size_t)v * 128 + c];
    s += val;
    q += val * val;
  }
  __shared__ float ls[2][128], lq[2][128];
  ls[half][c] = s;
  lq[half][c] = q;
  __syncthreads();
  if (threadIdx.x < 128) {
    atomicAdd(&stats[c], ls[0][c] + ls[1][c]);
    atomicAdd(&stats[128 + c], lq[0][c] + lq[1][c]);
  }
}

__global__ __launch_bounds__(128) void bn_final_kernel(const float* __restrict__ stats,
                                                       const float* __restrict__ gamma_l,
                                                       const float* __restrict__ beta_l,
                                                       float* __restrict__ ss, int n) {
  int c = threadIdx.x;
  float mean = stats[c] / (float)n;
  float var = stats[128 + c] / (float)n - mean * mean;
  float rs = rsqrtf(var + 1e-5f);
  float sc = gamma_l[c] * rs;
  ss[c] = sc;
  ss[128 + c] = beta_l[c] - mean * sc;
}

__global__ __launch_bounds__(256) void bn_apply_kernel(
    const float* __restrict__ z, const float* __restrict__ ss, float* __restrict__ h,
    __bf16* __restrict__ hhi, __bf16* __restrict__ hlo, int add_res, int n) {
  int idx = blockIdx.x * 256 + threadIdx.x;
  if (idx >= n * 128) return;
  int c = idx & 127;
  float val = z[idx] * ss[c] + ss[128 + c];
  if (add_res) val += h[idx];
  val = fmaxf(val, 0.f);
  h[idx] = val;
  __bf16 hi = (__bf16)val;
  hhi[idx] = hi;
  hlo[idx] = (__bf16)(val - (float)hi);
}

// ---------------- pooling, two-stage (batch = repeat(arange(B), N/B)) --------

#define POOL_SPLIT 8

__global__ __launch_bounds__(256) void pool_partial_kernel(const float* __restrict__ h,
                                                           float* __restrict__ part,
                                                           int npg) {
  int b = blockIdx.x, q = blockIdx.y;
  int half = threadIdx.x >> 7, c = threadIdx.x & 127;
  int rows = npg / POOL_SPLIT;
  const float* base = h + ((size_t)b * npg + q * rows) * 128;
  float s = 0.f;
  for (int r = half; r < rows; r += 2) s += base[(size_t)r * 128 + c];
  __shared__ float ls[2][128];
  ls[half][c] = s;
  __syncthreads();
  if (threadIdx.x < 128)
    part[((size_t)b * POOL_SPLIT + q) * 128 + c] = ls[0][c] + ls[1][c];
}

// ---------------- fused MLP head ---------------------------------------------

__global__ __launch_bounds__(128) void final_mlp_kernel(
    const float* __restrict__ part, float inv_npg, const float* __restrict__ gf,
    const float* __restrict__ mW1, const float* __restrict__ mb1,
    const float* __restrict__ mW2, const float* __restrict__ mb2,
    const float* __restrict__ gW1, const float* __restrict__ gb1,
    const float* __restrict__ gW2, const float* __restrict__ gb2,
    const float* __restrict__ fW1, const float* __restrict__ fb1,
    const float* __restrict__ fW2, const float* __restrict__ fb2,
    const float* __restrict__ fW3, const float* __restrict__ fb3,
    float* __restrict__ out) {
  int b = blockIdx.x, t = threadIdx.x;
  __shared__ float s1[16], s2[16], s1b[16], s2b[16];
  __shared__ float zv[160], t1[128], t2[64];

  if (t < 16) {
    float s = mb1[t];
    for (int i = 0; i < 4; i++) s += gf[b * 6 + i] * mW1[i * 16 + t];
    s1[t] = fmaxf(s, 0.f);
  } else if (t < 32) {
    int j = t - 16;
    float s = gb1[j];
    for (int i = 0; i < 2; i++) s += gf[b * 6 + 4 + i] * gW1[i * 16 + j];
    s2[j] = fmaxf(s, 0.f);
  }
  {
    float ps = 0.f;
#pragma unroll
    for (int q = 0; q < POOL_SPLIT; q++)
      ps += part[((size_t)b * POOL_SPLIT + q) * 128 + t];
    zv[t] = ps * inv_npg;
  }
  __syncthreads();
  if (t < 16) {
    float s = mb2[t];
    for (int i = 0; i < 16; i++) s += s1[i] * mW2[i * 16 + t];
    s1b[t] = fmaxf(s, 0.f);
  } else if (t < 32) {
    int j = t - 16;
    float s = gb2[j];
    for (int i = 0; i < 16; i++) s += s2[i] * gW2[i * 16 + j];
    s2b[j] = fmaxf(s, 0.f);
  }
  __syncthreads();
  if (t < 16)
    zv[128 + t] = s1b[t];
  else if (t < 32)
    zv[128 + t] = s2b[t - 16];
  __syncthreads();
  {
    float s = fb1[t];
    for (int i = 0; i < 160; i++) s += zv[i] * fW1[i * 128 + t];
    t1[t] = fmaxf(s, 0.f);
  }
  __syncthreads();
  if (t < 64) {
    float s = fb2[t];
    for (int i = 0; i < 128; i++) s += t1[i] * fW2[i * 64 + t];
    t2[t] = fmaxf(s, 0.f);
  }
  __syncthreads();
  if (t == 0) {
    float s = fb3[0];
    for (int i = 0; i < 64; i++) s += t2[i] * fW3[i];
    out[b] = s;
  }
}

// ---------------- host launcher ----------------------------------------------

extern "C" void kernel_launch(void* const* d_in, const int* in_sizes, int n_in,
                              void* d_out, int out_size, void* d_ws, size_t ws_size,
                              hipStream_t stream) {
  const float* x = (const float*)d_in[0];
  const int* ei = (const int*)d_in[1];
  const float* eattr = (const float*)d_in[2];
  const float* gf = (const float*)d_in[4];
  const float* W_emb = (const float*)d_in[5];
  const float* b_emb = (const float*)d_in[6];
  const float* Wl1 = (const float*)d_in[7];
  const float* Wr1 = (const float*)d_in[8];
  const float* Wl234 = (const float*)d_in[9];
  const float* Wr234 = (const float*)d_in[10];
  const float* bl = (const float*)d_in[11];
  const float* br = (const float*)d_in[12];
  const float* We = (const float*)d_in[13];
  const float* att = (const float*)d_in[14];
  const float* bo = (const float*)d_in[15];
  const float* gamma = (const float*)d_in[16];
  const float* beta = (const float*)d_in[17];
  const float* mW1 = (const float*)d_in[18];
  const float* mb1 = (const float*)d_in[19];
  const float* mW2 = (const float*)d_in[20];
  const float* mb2 = (const float*)d_in[21];
  const float* gW1 = (const float*)d_in[22];
  const float* gb1 = (const float*)d_in[23];
  const float* gW2 = (const float*)d_in[24];
  const float* gb2 = (const float*)d_in[25];
  const float* fW1 = (const float*)d_in[26];
  const float* fb1 = (const float*)d_in[27];
  const float* fW2 = (const float*)d_in[28];
  const float* fb2 = (const float*)d_in[29];
  const float* fW3 = (const float*)d_in[30];
  const float* fb3 = (const float*)d_in[31];

  const int N = in_sizes[0] / 4;
  const int E = in_sizes[2];
  const int B = in_sizes[4] / 6;
  const int G = (N + 255) / 256;  // scan blocks (157)

  char* wsb = (char*)d_ws;
  size_t off = 0;
  auto alloc = [&](size_t bytes) {
    size_t r = off;
    off += (bytes + 255) & ~(size_t)255;
    return r;
  };
  float* h = (float*)(wsb + alloc((size_t)N * 128 * 4));
  float* z = (float*)(wsb + alloc((size_t)N * 128 * 4));
  float* xlr = (float*)(wsb + alloc((size_t)N * 256 * 4));
  __bf16* hhi = (__bf16*)(wsb + alloc((size_t)N * 128 * 2));
  __bf16* hlo = (__bf16*)(wsb + alloc((size_t)N * 128 * 2));
  __bf16* h0hi = (__bf16*)(wsb + alloc((size_t)N * 64 * 2));
  __bf16* h0lo = (__bf16*)(wsb + alloc((size_t)N * 64 * 2));
  __bf16* wtHi = (__bf16*)(wsb + alloc((size_t)256 * 128 * 2));
  __bf16* wtLo = (__bf16*)(wsb + alloc((size_t)256 * 128 * 2));
  int* csr_src = (int*)(wsb + alloc((size_t)(E + N) * 4));
  float* csr_ea = (float*)(wsb + alloc((size_t)(E + N) * 4));
  int* row_ofs = (int*)(wsb + alloc((size_t)(N + 1) * 4));
  int* cursor = (int*)(wsb + alloc((size_t)N * 4));
  int* deg = (int*)(wsb + alloc((size_t)N * 4));
  int* bsum = (int*)(wsb + alloc((size_t)(G + 1) * 4));
  int* bofs = (int*)(wsb + alloc((size_t)(G + 1) * 4));
  float* stats = (float*)(wsb + alloc(256 * 4));
  float* ss = (float*)(wsb + alloc(256 * 4));
  float* ea_sum = (float*)(wsb + alloc(256));
  float* part = (float*)(wsb + alloc((size_t)B * POOL_SPLIT * 128 * 4));
  (void)ws_size;
  (void)n_in;
  (void)out_size;

  // ---- CSR build ----
  hipMemsetAsync(ea_sum, 0, 4, stream);
  init_deg_kernel<<<(N + 255) / 256, 256, 0, stream>>>(deg, N);
  count_kernel<<<(E + 255) / 256, 256, 0, stream>>>(ei, eattr, deg, ea_sum, E);
  block_sum_kernel<<<G, 256, 0, stream>>>(deg, bsum, N);
  scan_sums_kernel<<<1, 256, 0, stream>>>(bsum, bofs, G);
  write_ofs_kernel<<<G, 256, 0, stream>>>(deg, bofs, row_ofs, N);
  copy_int_kernel<<<(N + 255) / 256, 256, 0, stream>>>(row_ofs, cursor, N);
  fill_kernel<<<(E + N + 255) / 256, 256, 0, stream>>>(ei, eattr, ea_sum, cursor,
                                                       csr_src, csr_ea, E, N);

  // ---- embed (emits bf16 hi/lo splits directly) ----
  embed_kernel<<<(N * 64 + 255) / 256, 256, 0, stream>>>(x, W_emb, b_emb, h0hi, h0lo, N);

  // ---- 4 GAT layers ----
  for (int L = 0; L < 4; ++L) {
    int K = (L == 0) ? 64 : 128;
    const __bf16* hA = (L == 0) ? h0hi : hhi;
    const __bf16* lA = (L == 0) ? h0lo : hlo;
    const float* Wl_p = (L == 0) ? Wl1 : Wl234 + (size_t)(L - 1) * 128 * 128;
    const float* Wr_p = (L == 0) ? Wr1 : Wr234 + (size_t)(L - 1) * 128 * 128;

    w_split_kernel<<<K, 256, 0, stream>>>(Wl_p, Wr_p, wtHi, wtLo, K);
    gemm_mfma_kernel<<<dim3(4, N / 64), 256, 0, stream>>>(hA, lA, wtHi, wtLo,
                                                          bl + L * 128, br + L * 128,
                                                          xlr, K);
    gat_kernel<<<(N + 3) / 4, 256, 0, stream>>>(xlr, row_ofs, csr_src, csr_ea,
                                                We + L * 128, att + L * 128,
                                                bo + L * 128, z, N);
    hipMemsetAsync(stats, 0, 256 * 4, stream);
    bn_stats_kernel<<<256, 256, 0, stream>>>(z, stats, N);
    bn_final_kernel<<<1, 128, 0, stream>>>(stats, gamma + L * 128, beta + L * 128, ss, N);
    bn_apply_kernel<<<(N * 128 + 255) / 256, 256, 0, stream>>>(z, ss, h, hhi, hlo,
                                                               (L == 0) ? 0 : 1, N);
  }

  // ---- pool + head ----
  pool_partial_kernel<<<dim3(B, POOL_SPLIT), 256, 0, stream>>>(h, part, N / B);
  final_mlp_kernel<<<B, 128, 0, stream>>>(part, (float)B / (float)N, gf, mW1, mb1, mW2,
                                          mb2, gW1, gb1, gW2, gb2, fW1, fb1, fW2, fb2,
                                          fW3, fb3, (float*)d_out);
}